// Round 5
// baseline (824.848 us; speedup 1.0000x reference)
//
#include <hip/hip_runtime.h>
#include <stdint.h>

typedef float vfloat4 __attribute__((ext_vector_type(4)));

// B=1024, N=8192, D=128
// out layout (floats): quantized[1024][1024][128] | ind[1024] | loss[1]
static const long long QN       = 134217728LL;
static const long long IND_OFF  = QN;
static const long long LOSS_OFF = QN + 1024;

// ws layout (float offsets). ws is 2 GiB; we use ~600 KB.
#define WS_W2    0        // 8192 floats
#define WS_X2    8192     // 1024
#define WS_SX    9216     // 128
#define WS_PVAL  16384    // 65536 floats (1024 x 64)
#define WS_PIDX  81920    // 65536 ints

// Fused prep: blocks 0-31 w2 rows; 32-35 x2 rows; 36-39 x column-sums
// (each block owns 32 columns — no atomics).
__global__ __launch_bounds__(256) void k_prep(const float* __restrict__ x,
                                              const float* __restrict__ W,
                                              float* __restrict__ ws) {
    const int b = blockIdx.x, tid = threadIdx.x;
    if (b < 36) {
        const float4* pr = (b < 32) ? ((const float4*)W + (size_t)(b * 256 + tid) * 32)
                                    : ((const float4*)x + (size_t)((b - 32) * 256 + tid) * 32);
        float s = 0.0f;
#pragma unroll 8
        for (int t = 0; t < 32; ++t) {
            float4 v = pr[t];
            s += v.x * v.x + v.y * v.y + v.z * v.z + v.w * v.w;
        }
        if (b < 32) ws[WS_W2 + b * 256 + tid] = s;
        else        ws[WS_X2 + (b - 32) * 256 + tid] = s;
    } else {
        __shared__ float sh[8][32];
        const int c = tid & 31, g = tid >> 5;
        const int col = (b - 36) * 32 + c;
        float sum = 0.0f;
        for (int r = g; r < 1024; r += 8) sum += x[(size_t)r * 128 + col];
        sh[g][c] = sum;
        __syncthreads();
        if (g == 0) {
            float t = 0.0f;
#pragma unroll
            for (int gg = 0; gg < 8; ++gg) t += sh[gg][c];
            ws[WS_SX + col] = t;
        }
    }
}

// dist[m][n] with the reference's fp32 rounding:
//   t = x2[m] - 2*dot(x_m,W_n); s = t + w2[n]
// Per-block partial argmin (first-occurrence tie-break) over a 128-col chunk.
// BYTE-IDENTICAL to the proven 623 us round-3 version (unroll 8). Two
// attempted "improvements" (vfloat2 acc, unroll 4) each cost 40-50 us —
// this codegen is a local optimum. DO NOT PERTURB.
__global__ __launch_bounds__(256) void k_score(
    const float* __restrict__ x, const float* __restrict__ W,
    const float* __restrict__ w2, const float* __restrict__ x2,
    float* __restrict__ pval, int* __restrict__ pidx) {
    __shared__ float Xs[32][132];  // [k][m], +4 pad
    __shared__ float Wst[32][132]; // [k][n]
    const int tid = threadIdx.x;
    const int tx = tid & 15, ty = tid >> 4;
    const int n0 = blockIdx.x * 128, m0 = blockIdx.y * 128;
    const float4* xv = (const float4*)x;
    const float4* wv = (const float4*)W;

    float acc[8][8];
#pragma unroll
    for (int i = 0; i < 8; ++i)
#pragma unroll
        for (int j = 0; j < 8; ++j) acc[i][j] = 0.0f;

    for (int kc = 0; kc < 4; ++kc) {
#pragma unroll
        for (int it = 0; it < 4; ++it) {
            int f = it * 256 + tid;
            int m = f >> 3, kq = f & 7;
            float4 a = xv[(size_t)(m0 + m) * 32 + kc * 8 + kq];
            float4 b = wv[(size_t)(n0 + m) * 32 + kc * 8 + kq];
            Xs[kq * 4 + 0][m] = a.x;
            Xs[kq * 4 + 1][m] = a.y;
            Xs[kq * 4 + 2][m] = a.z;
            Xs[kq * 4 + 3][m] = a.w;
            Wst[kq * 4 + 0][m] = b.x;
            Wst[kq * 4 + 1][m] = b.y;
            Wst[kq * 4 + 2][m] = b.z;
            Wst[kq * 4 + 3][m] = b.w;
        }
        __syncthreads();
#pragma unroll 8
        for (int k = 0; k < 32; ++k) {
            float4 a0 = *(const float4*)&Xs[k][ty * 8];
            float4 a1 = *(const float4*)&Xs[k][ty * 8 + 4];
            float4 b0 = *(const float4*)&Wst[k][tx * 8];
            float4 b1 = *(const float4*)&Wst[k][tx * 8 + 4];
            float af[8] = {a0.x, a0.y, a0.z, a0.w, a1.x, a1.y, a1.z, a1.w};
            float bf[8] = {b0.x, b0.y, b0.z, b0.w, b1.x, b1.y, b1.z, b1.w};
#pragma unroll
            for (int i = 0; i < 8; ++i)
#pragma unroll
                for (int j = 0; j < 8; ++j) acc[i][j] += af[i] * bf[j];
        }
        __syncthreads();
    }

    float w2v[8];
#pragma unroll
    for (int j = 0; j < 8; ++j) w2v[j] = w2[n0 + tx * 8 + j];

#pragma unroll
    for (int i = 0; i < 8; ++i) {
        const int row = m0 + ty * 8 + i;
        const float xxv = x2[row];
        float bestv;
        int besti = n0 + tx * 8;
        {
            float t = xxv - 2.0f * acc[i][0];
            bestv = t + w2v[0];
        }
#pragma unroll
        for (int j = 1; j < 8; ++j) {
            float t = xxv - 2.0f * acc[i][j];
            float s = t + w2v[j];
            if (s < bestv) { bestv = s; besti = n0 + tx * 8 + j; }
        }
        for (int off = 1; off < 16; off <<= 1) {
            float ov = __shfl_xor(bestv, off, 64);
            int oi = __shfl_xor(besti, off, 64);
            if (ov < bestv || (ov == bestv && oi < besti)) { bestv = ov; besti = oi; }
        }
        if (tx == 0) {
            pval[row * 64 + blockIdx.x] = bestv;
            pidx[row * 64 + blockIdx.x] = besti;
        }
    }
}

// Fused argmin + broadcast (plain stores — the nt-store experiment is
// removed as a confound). Each block (row i = bid>>3, eighth e = bid&7):
// wave 0 re-derives row i's argmin from pval/pidx (butterfly min with
// (val, min-idx) tie-break == first-occurrence scan, since chunk c only holds
// indices in [c*128, c*128+128)), gathers W[ind] (L2-hot), streams its 64 KB
// eighth. e==0 block writes ind. Block 0 additionally computes the loss —
// ~25 us of L2-resident work hidden under the ~86 us write stream.
__global__ __launch_bounds__(256) void k_bcast(
    const float* __restrict__ W,
    const float* __restrict__ pval, const int* __restrict__ pidx,
    float* __restrict__ out, const float* __restrict__ ws) {
    const int bid = blockIdx.x, tid = threadIdx.x;
    const int i = bid >> 3;          // row 0..1023
    const int e = bid & 7;           // eighth of the j range
    __shared__ float qrow[128];
    __shared__ int sbesti;
    if (tid < 64) {
        float bestv = pval[i * 64 + tid];
        int besti = pidx[i * 64 + tid];
        for (int off = 1; off < 64; off <<= 1) {
            float ov = __shfl_xor(bestv, off, 64);
            int oi = __shfl_xor(besti, off, 64);
            if (ov < bestv || (ov == bestv && oi < besti)) { bestv = ov; besti = oi; }
        }
        if (tid == 0) {
            sbesti = besti;
            if (e == 0) out[IND_OFF + i] = (float)besti;
        }
    }
    __syncthreads();
    const int idx = sbesti;
    if (tid < 32) ((float4*)qrow)[tid] = ((const float4*)W)[(size_t)idx * 32 + tid];
    __syncthreads();

    const int t = tid & 31;
    vfloat4 qv = ((const vfloat4*)qrow)[t];
    vfloat4* dst = (vfloat4*)out + (size_t)i * 32768 + t;
    const int jend = e * 128 + 128;
    for (int j = e * 128 + (tid >> 5); j < jend; j += 8) {
        dst[(size_t)j * 32] = qv;
    }

    if (bid == 0) {
        __shared__ int sind[1024];
        __shared__ float shd[2][128];
        __shared__ float sh[256];
#pragma unroll
        for (int rr = 0; rr < 4; ++rr) {
            const int r = rr * 256 + tid;
            float bv = pval[r * 64];
            int bi = pidx[r * 64];
            for (int c = 1; c < 64; ++c) {
                float v = pval[r * 64 + c];
                if (v < bv) { bv = v; bi = pidx[r * 64 + c]; }
            }
            sind[r] = bi;
        }
        __syncthreads();
        const int d = tid & 127, g = tid >> 7;
        float s = 0.0f;
        for (int r = g; r < 1024; r += 2) s += W[(size_t)sind[r] * 128 + d];
        shd[g][d] = s;
        __syncthreads();
        float dotv = (tid < 128) ? (shd[0][tid] + shd[1][tid]) * ws[WS_SX + tid] : 0.0f;
        float sx2 = 0.0f, sq2 = 0.0f;
        for (int r = tid; r < 1024; r += 256) {
            sx2 += ws[WS_X2 + r];
            sq2 += ws[WS_W2 + sind[r]];
        }
        sh[tid] = dotv;
        __syncthreads();
        for (int st = 128; st > 0; st >>= 1) {
            if (tid < st) sh[tid] += sh[tid + st];
            __syncthreads();
        }
        const float dot = sh[0];
        __syncthreads();
        sh[tid] = sx2;
        __syncthreads();
        for (int st = 128; st > 0; st >>= 1) {
            if (tid < st) sh[tid] += sh[tid + st];
            __syncthreads();
        }
        const float Sx2 = sh[0];
        __syncthreads();
        sh[tid] = sq2;
        __syncthreads();
        for (int st = 128; st > 0; st >>= 1) {
            if (tid < st) sh[tid] += sh[tid + st];
            __syncthreads();
        }
        if (tid == 0) {
            double loss = 1.25 * (1024.0 * (double)Sx2 + 1024.0 * (double)sh[0] - 2.0 * (double)dot) / 134217728.0;
            out[LOSS_OFF] = (float)loss;
        }
    }
}

extern "C" void kernel_launch(void* const* d_in, const int* in_sizes, int n_in,
                              void* d_out, int out_size, void* d_ws, size_t ws_size,
                              hipStream_t stream) {
    const float* x = (const float*)d_in[0]; // 1024 x 128
    const float* W = (const float*)d_in[1]; // 8192 x 128
    float* out = (float*)d_out;
    float* ws = (float*)d_ws;

    hipLaunchKernelGGL(k_prep, dim3(40), dim3(256), 0, stream, x, W, ws);
    hipLaunchKernelGGL(k_score, dim3(64, 8), dim3(256), 0, stream, x, W,
                       ws + WS_W2, ws + WS_X2, ws + WS_PVAL, (int*)(ws + WS_PIDX));
    hipLaunchKernelGGL(k_bcast, dim3(8192), dim3(256), 0, stream,
                       W, ws + WS_PVAL, (const int*)(ws + WS_PIDX), out, ws);
}

// Round 7
// 622.682 us; speedup vs baseline: 1.3247x; 1.3247x over previous
//
#include <hip/hip_runtime.h>
#include <stdint.h>

typedef float vfloat4 __attribute__((ext_vector_type(4)));

// B=1024, N=8192, D=128
// out layout (floats): quantized[1024][1024][128] | ind[1024] | loss[1]
static const long long QN       = 134217728LL;
static const long long IND_OFF  = QN;
static const long long LOSS_OFF = QN + 1024;

// ws layout (float offsets). ws is 2 GiB; we use ~1.1 MB.
#define WS_W2    0        // 8192 floats
#define WS_X2    8192     // 1024
#define WS_SX    9216     // 128
#define WS_SQ    9344     // 128
#define WS_SQ2   9472     // 1
#define WS_PVAL  16384    // 65536 floats (1024 x 64)
#define WS_PIDX  81920    // 65536 ints
#define WS_Q     147456   // 131072 floats (1024 x 128 gathered codes)

// EXACT RE-BENCH of the round-3 source (measured 623.0 us) — repeat
// measurement on a fresh container to separate cross-container noise from
// real kernel deltas. (Round-6 attempt was an infra failure; resubmitting.)

// Fused prep: blocks 0-31 w2 rows; 32-35 x2 rows; 36-39 x column-sums
// (each block owns 32 columns — no atomics) + block 36 zeros sq/Sq2.
__global__ __launch_bounds__(256) void k_prep(const float* __restrict__ x,
                                              const float* __restrict__ W,
                                              float* __restrict__ ws) {
    const int b = blockIdx.x, tid = threadIdx.x;
    if (b < 36) {
        const float4* pr = (b < 32) ? ((const float4*)W + (size_t)(b * 256 + tid) * 32)
                                    : ((const float4*)x + (size_t)((b - 32) * 256 + tid) * 32);
        float s = 0.0f;
#pragma unroll 8
        for (int t = 0; t < 32; ++t) {
            float4 v = pr[t];
            s += v.x * v.x + v.y * v.y + v.z * v.z + v.w * v.w;
        }
        if (b < 32) ws[WS_W2 + b * 256 + tid] = s;
        else        ws[WS_X2 + (b - 32) * 256 + tid] = s;
    } else {
        __shared__ float sh[8][32];
        const int c = tid & 31, g = tid >> 5;
        const int col = (b - 36) * 32 + c;
        float sum = 0.0f;
        for (int r = g; r < 1024; r += 8) sum += x[(size_t)r * 128 + col];
        sh[g][c] = sum;
        __syncthreads();
        if (g == 0) {
            float t = 0.0f;
#pragma unroll
            for (int gg = 0; gg < 8; ++gg) t += sh[gg][c];
            ws[WS_SX + col] = t;
        }
        if (b == 36 && tid < 129) ws[WS_SQ + tid] = 0.0f; // sq[128] + Sq2
    }
}

// dist[m][n] with the reference's fp32 rounding:
//   t = x2[m] - 2*dot(x_m,W_n); s = t + w2[n]
// Per-block partial argmin (first-occurrence tie-break) over a 128-col chunk.
// VERIFIED CORRECT — byte-identical to the 638/623 us versions. DO NOT PERTURB.
__global__ __launch_bounds__(256) void k_score(
    const float* __restrict__ x, const float* __restrict__ W,
    const float* __restrict__ w2, const float* __restrict__ x2,
    float* __restrict__ pval, int* __restrict__ pidx) {
    __shared__ float Xs[32][132];  // [k][m], +4 pad
    __shared__ float Wst[32][132]; // [k][n]
    const int tid = threadIdx.x;
    const int tx = tid & 15, ty = tid >> 4;
    const int n0 = blockIdx.x * 128, m0 = blockIdx.y * 128;
    const float4* xv = (const float4*)x;
    const float4* wv = (const float4*)W;

    float acc[8][8];
#pragma unroll
    for (int i = 0; i < 8; ++i)
#pragma unroll
        for (int j = 0; j < 8; ++j) acc[i][j] = 0.0f;

    for (int kc = 0; kc < 4; ++kc) {
#pragma unroll
        for (int it = 0; it < 4; ++it) {
            int f = it * 256 + tid;
            int m = f >> 3, kq = f & 7;
            float4 a = xv[(size_t)(m0 + m) * 32 + kc * 8 + kq];
            float4 b = wv[(size_t)(n0 + m) * 32 + kc * 8 + kq];
            Xs[kq * 4 + 0][m] = a.x;
            Xs[kq * 4 + 1][m] = a.y;
            Xs[kq * 4 + 2][m] = a.z;
            Xs[kq * 4 + 3][m] = a.w;
            Wst[kq * 4 + 0][m] = b.x;
            Wst[kq * 4 + 1][m] = b.y;
            Wst[kq * 4 + 2][m] = b.z;
            Wst[kq * 4 + 3][m] = b.w;
        }
        __syncthreads();
#pragma unroll 8
        for (int k = 0; k < 32; ++k) {
            float4 a0 = *(const float4*)&Xs[k][ty * 8];
            float4 a1 = *(const float4*)&Xs[k][ty * 8 + 4];
            float4 b0 = *(const float4*)&Wst[k][tx * 8];
            float4 b1 = *(const float4*)&Wst[k][tx * 8 + 4];
            float af[8] = {a0.x, a0.y, a0.z, a0.w, a1.x, a1.y, a1.z, a1.w};
            float bf[8] = {b0.x, b0.y, b0.z, b0.w, b1.x, b1.y, b1.z, b1.w};
#pragma unroll
            for (int i = 0; i < 8; ++i)
#pragma unroll
                for (int j = 0; j < 8; ++j) acc[i][j] += af[i] * bf[j];
        }
        __syncthreads();
    }

    float w2v[8];
#pragma unroll
    for (int j = 0; j < 8; ++j) w2v[j] = w2[n0 + tx * 8 + j];

#pragma unroll
    for (int i = 0; i < 8; ++i) {
        const int row = m0 + ty * 8 + i;
        const float xxv = x2[row];
        float bestv;
        int besti = n0 + tx * 8;
        {
            float t = xxv - 2.0f * acc[i][0];
            bestv = t + w2v[0];
        }
#pragma unroll
        for (int j = 1; j < 8; ++j) {
            float t = xxv - 2.0f * acc[i][j];
            float s = t + w2v[j];
            if (s < bestv) { bestv = s; besti = n0 + tx * 8 + j; }
        }
        for (int off = 1; off < 16; off <<= 1) {
            float ov = __shfl_xor(bestv, off, 64);
            int oi = __shfl_xor(besti, off, 64);
            if (ov < bestv || (ov == bestv && oi < besti)) { bestv = ov; besti = oi; }
        }
        if (tx == 0) {
            pval[row * 64 + blockIdx.x] = bestv;
            pidx[row * 64 + blockIdx.x] = besti;
        }
    }
}

// Final argmin per row. Round-0 structure (sq via atomics, Sq2 = w2[ind]),
// 16 blocks x 64 rows. Wave-per-row butterfly min with (val, min-idx)
// tie-break == first-occurrence scan, since pidx from column-chunk c only
// contains indices in [c*128, c*128+128).
__global__ __launch_bounds__(256) void k_argmin(
    const float* __restrict__ W, const float* __restrict__ w2,
    const float* __restrict__ pval, const int* __restrict__ pidx,
    float* __restrict__ out, float* __restrict__ ws) {
    __shared__ int sidx[64];
    __shared__ float sh[2][128];
    const int tid = threadIdx.x;
    const int w = tid >> 6, lane = tid & 63;
    const int r0 = blockIdx.x * 64;
    float q2 = 0.0f;
#pragma unroll 4
    for (int it = 0; it < 16; ++it) {
        const int rr = it * 4 + w;       // local row 0..63
        const int r = r0 + rr;
        float bestv = pval[r * 64 + lane];
        int besti = pidx[r * 64 + lane];
        for (int off = 1; off < 64; off <<= 1) {
            float ov = __shfl_xor(bestv, off, 64);
            int oi = __shfl_xor(besti, off, 64);
            if (ov < bestv || (ov == bestv && oi < besti)) { bestv = ov; besti = oi; }
        }
        if (lane == 0) {
            out[IND_OFF + r] = (float)besti;
            sidx[rr] = besti;
            q2 += w2[besti];             // ||q_r||^2 == w2[ind_r]
        }
    }
    if (lane == 0) atomicAdd(ws + WS_SQ2, q2);
    __syncthreads();

    // Coalesced q gather into ws: 8 iters of (8 rows x 32 float4)
    const int c4 = tid & 31, rg = tid >> 5;
    float4* wsq = (float4*)(ws + WS_Q);
    const float4* wv = (const float4*)W;
#pragma unroll
    for (int it = 0; it < 8; ++it) {
        int rr = it * 8 + rg;
        int idx = sidx[rr];
        wsq[(size_t)(r0 + rr) * 32 + c4] = wv[(size_t)idx * 32 + c4];
    }

    // Column sums of q over this block's 64 rows (L2-hot rows of W)
    const int d = tid & 127, g = tid >> 7;
    float s = 0.0f;
    for (int rr = g; rr < 64; rr += 2) s += W[(size_t)sidx[rr] * 128 + d];
    sh[g][d] = s;
    __syncthreads();
    if (g == 0) atomicAdd(ws + WS_SQ + d, sh[0][d] + sh[1][d]);
}

// quantized[i][j][:] = q[i]. 537 MB stream write; 8192 blocks x 64 KB.
// Block 0 additionally computes the loss scalar first (from precomputed
// sq/Sq2/x2/sx).
__global__ __launch_bounds__(256) void k_bcast(float* __restrict__ out,
                                               const float* __restrict__ ws) {
    const int bid = blockIdx.x, tid = threadIdx.x;
    if (bid == 0) {
        __shared__ float sh[256];
        float dotv = (tid < 128) ? ws[WS_SX + tid] * ws[WS_SQ + tid] : 0.0f;
        float sx2 = 0.0f;
        for (int r = tid; r < 1024; r += 256) sx2 += ws[WS_X2 + r];
        sh[tid] = dotv;
        __syncthreads();
        for (int s = 128; s > 0; s >>= 1) {
            if (tid < s) sh[tid] += sh[tid + s];
            __syncthreads();
        }
        const float dot = sh[0];
        __syncthreads();
        sh[tid] = sx2;
        __syncthreads();
        for (int s = 128; s > 0; s >>= 1) {
            if (tid < s) sh[tid] += sh[tid + s];
            __syncthreads();
        }
        if (tid == 0) {
            double Sx2 = (double)sh[0], Sq2 = (double)ws[WS_SQ2];
            double loss = 1.25 * (1024.0 * Sx2 + 1024.0 * Sq2 - 2.0 * (double)dot) / 134217728.0;
            out[LOSS_OFF] = (float)loss;
        }
        __syncthreads();
    }
    const int i = bid >> 3;          // row 0..1023
    const int e = bid & 7;           // eighth of the j range
    const int t = tid & 31;
    const vfloat4* src = (const vfloat4*)(ws + WS_Q) + (size_t)i * 32;
    vfloat4 qv = src[t];
    vfloat4* dst = (vfloat4*)out + (size_t)i * 32768 + t;
    const int jend = e * 128 + 128;
    for (int j = e * 128 + (tid >> 5); j < jend; j += 8) {
        dst[(size_t)j * 32] = qv;
    }
}

extern "C" void kernel_launch(void* const* d_in, const int* in_sizes, int n_in,
                              void* d_out, int out_size, void* d_ws, size_t ws_size,
                              hipStream_t stream) {
    const float* x = (const float*)d_in[0]; // 1024 x 128
    const float* W = (const float*)d_in[1]; // 8192 x 128
    float* out = (float*)d_out;
    float* ws = (float*)d_ws;

    hipLaunchKernelGGL(k_prep, dim3(40), dim3(256), 0, stream, x, W, ws);
    hipLaunchKernelGGL(k_score, dim3(64, 8), dim3(256), 0, stream, x, W,
                       ws + WS_W2, ws + WS_X2, ws + WS_PVAL, (int*)(ws + WS_PIDX));
    hipLaunchKernelGGL(k_argmin, dim3(16), dim3(256), 0, stream, W, ws + WS_W2,
                       ws + WS_PVAL, (const int*)(ws + WS_PIDX), out, ws);
    hipLaunchKernelGGL(k_bcast, dim3(8192), dim3(256), 0, stream, out, ws);
}

// Round 8
// 620.676 us; speedup vs baseline: 1.3290x; 1.0032x over previous
//
#include <hip/hip_runtime.h>
#include <stdint.h>

typedef float vfloat4 __attribute__((ext_vector_type(4)));

// B=1024, N=8192, D=128
// out layout (floats): quantized[1024][1024][128] | ind[1024] | loss[1]
static const long long QN       = 134217728LL;
static const long long IND_OFF  = QN;
static const long long LOSS_OFF = QN + 1024;

// ws layout (float offsets). ws is 2 GiB; we use ~1.1 MB.
#define WS_W2    0        // 8192 floats
#define WS_X2    8192     // 1024
#define WS_SX    9216     // 128
#define WS_SQ    9344     // 128
#define WS_SQ2   9472     // 1
#define WS_PVAL  16384    // 65536 floats (1024 x 64)
#define WS_PIDX  81920    // 65536 ints
#define WS_Q     147456   // 131072 floats (1024 x 128 gathered codes)

// Fused prep: blocks 0-31 w2 rows; 32-35 x2 rows; 36-39 x column-sums
// (each block owns 32 columns — no atomics) + block 36 zeros sq/Sq2.
// Byte-identical to the proven 622.7 us version.
__global__ __launch_bounds__(256) void k_prep(const float* __restrict__ x,
                                              const float* __restrict__ W,
                                              float* __restrict__ ws) {
    const int b = blockIdx.x, tid = threadIdx.x;
    if (b < 36) {
        const float4* pr = (b < 32) ? ((const float4*)W + (size_t)(b * 256 + tid) * 32)
                                    : ((const float4*)x + (size_t)((b - 32) * 256 + tid) * 32);
        float s = 0.0f;
#pragma unroll 8
        for (int t = 0; t < 32; ++t) {
            float4 v = pr[t];
            s += v.x * v.x + v.y * v.y + v.z * v.z + v.w * v.w;
        }
        if (b < 32) ws[WS_W2 + b * 256 + tid] = s;
        else        ws[WS_X2 + (b - 32) * 256 + tid] = s;
    } else {
        __shared__ float sh[8][32];
        const int c = tid & 31, g = tid >> 5;
        const int col = (b - 36) * 32 + c;
        float sum = 0.0f;
        for (int r = g; r < 1024; r += 8) sum += x[(size_t)r * 128 + col];
        sh[g][c] = sum;
        __syncthreads();
        if (g == 0) {
            float t = 0.0f;
#pragma unroll
            for (int gg = 0; gg < 8; ++gg) t += sh[gg][c];
            ws[WS_SX + col] = t;
        }
        if (b == 36 && tid < 129) ws[WS_SQ + tid] = 0.0f; // sq[128] + Sq2
    }
}

// dist[m][n] with the reference's fp32 rounding:
//   t = x2[m] - 2*dot(x_m,W_n); s = t + w2[n]
// ROUND-8 CHANGE (tile decomposition only): 128x128 -> 64(m)x128(n) tile,
// grid (64,16) = 1024 blocks = 4 blocks/CU (4 independent barrier domains,
// was 2). LDS 25.9 KB/block. Per-thread acc 8x8 -> 4x8. The k-loop keeps
// unroll 8, float4 LDS reads, and the SAME per-(m,n) FMA chain order ->
// bit-identical accumulator values. pval/pidx layout unchanged.
__global__ __launch_bounds__(256, 4) void k_score(
    const float* __restrict__ x, const float* __restrict__ W,
    const float* __restrict__ w2, const float* __restrict__ x2,
    float* __restrict__ pval, int* __restrict__ pidx) {
    __shared__ float Xs[32][68];   // [k][m], +4 pad
    __shared__ float Wst[32][132]; // [k][n], +4 pad
    const int tid = threadIdx.x;
    const int tx = tid & 15, ty = tid >> 4;
    const int n0 = blockIdx.x * 128, m0 = blockIdx.y * 64;
    const float4* xv = (const float4*)x;
    const float4* wv = (const float4*)W;

    float acc[4][8];
#pragma unroll
    for (int i = 0; i < 4; ++i)
#pragma unroll
        for (int j = 0; j < 8; ++j) acc[i][j] = 0.0f;

    for (int kc = 0; kc < 4; ++kc) {
#pragma unroll
        for (int it = 0; it < 2; ++it) {   // x tile: 64 rows x 8 float4
            int f = it * 256 + tid;
            int m = f >> 3, kq = f & 7;
            float4 a = xv[(size_t)(m0 + m) * 32 + kc * 8 + kq];
            Xs[kq * 4 + 0][m] = a.x;
            Xs[kq * 4 + 1][m] = a.y;
            Xs[kq * 4 + 2][m] = a.z;
            Xs[kq * 4 + 3][m] = a.w;
        }
#pragma unroll
        for (int it = 0; it < 4; ++it) {   // W tile: 128 rows x 8 float4
            int f = it * 256 + tid;
            int n = f >> 3, kq = f & 7;
            float4 b = wv[(size_t)(n0 + n) * 32 + kc * 8 + kq];
            Wst[kq * 4 + 0][n] = b.x;
            Wst[kq * 4 + 1][n] = b.y;
            Wst[kq * 4 + 2][n] = b.z;
            Wst[kq * 4 + 3][n] = b.w;
        }
        __syncthreads();
#pragma unroll 8
        for (int k = 0; k < 32; ++k) {
            float4 a0 = *(const float4*)&Xs[k][ty * 4];
            float4 b0 = *(const float4*)&Wst[k][tx * 8];
            float4 b1 = *(const float4*)&Wst[k][tx * 8 + 4];
            float af[4] = {a0.x, a0.y, a0.z, a0.w};
            float bf[8] = {b0.x, b0.y, b0.z, b0.w, b1.x, b1.y, b1.z, b1.w};
#pragma unroll
            for (int i = 0; i < 4; ++i)
#pragma unroll
                for (int j = 0; j < 8; ++j) acc[i][j] += af[i] * bf[j];
        }
        __syncthreads();
    }

    float w2v[8];
#pragma unroll
    for (int j = 0; j < 8; ++j) w2v[j] = w2[n0 + tx * 8 + j];

#pragma unroll
    for (int i = 0; i < 4; ++i) {
        const int row = m0 + ty * 4 + i;
        const float xxv = x2[row];
        float bestv;
        int besti = n0 + tx * 8;
        {
            float t = xxv - 2.0f * acc[i][0];
            bestv = t + w2v[0];
        }
#pragma unroll
        for (int j = 1; j < 8; ++j) {
            float t = xxv - 2.0f * acc[i][j];
            float s = t + w2v[j];
            if (s < bestv) { bestv = s; besti = n0 + tx * 8 + j; }
        }
        for (int off = 1; off < 16; off <<= 1) {
            float ov = __shfl_xor(bestv, off, 64);
            int oi = __shfl_xor(besti, off, 64);
            if (ov < bestv || (ov == bestv && oi < besti)) { bestv = ov; besti = oi; }
        }
        if (tx == 0) {
            pval[row * 64 + blockIdx.x] = bestv;
            pidx[row * 64 + blockIdx.x] = besti;
        }
    }
}

// Final argmin per row. 16 blocks x 64 rows. Wave-per-row butterfly min with
// (val, min-idx) tie-break == first-occurrence scan, since pidx from
// column-chunk c only contains indices in [c*128, c*128+128).
// Byte-identical to the proven 622.7 us version.
__global__ __launch_bounds__(256) void k_argmin(
    const float* __restrict__ W, const float* __restrict__ w2,
    const float* __restrict__ pval, const int* __restrict__ pidx,
    float* __restrict__ out, float* __restrict__ ws) {
    __shared__ int sidx[64];
    __shared__ float sh[2][128];
    const int tid = threadIdx.x;
    const int w = tid >> 6, lane = tid & 63;
    const int r0 = blockIdx.x * 64;
    float q2 = 0.0f;
#pragma unroll 4
    for (int it = 0; it < 16; ++it) {
        const int rr = it * 4 + w;       // local row 0..63
        const int r = r0 + rr;
        float bestv = pval[r * 64 + lane];
        int besti = pidx[r * 64 + lane];
        for (int off = 1; off < 64; off <<= 1) {
            float ov = __shfl_xor(bestv, off, 64);
            int oi = __shfl_xor(besti, off, 64);
            if (ov < bestv || (ov == bestv && oi < besti)) { bestv = ov; besti = oi; }
        }
        if (lane == 0) {
            out[IND_OFF + r] = (float)besti;
            sidx[rr] = besti;
            q2 += w2[besti];             // ||q_r||^2 == w2[ind_r]
        }
    }
    if (lane == 0) atomicAdd(ws + WS_SQ2, q2);
    __syncthreads();

    // Coalesced q gather into ws: 8 iters of (8 rows x 32 float4)
    const int c4 = tid & 31, rg = tid >> 5;
    float4* wsq = (float4*)(ws + WS_Q);
    const float4* wv = (const float4*)W;
#pragma unroll
    for (int it = 0; it < 8; ++it) {
        int rr = it * 8 + rg;
        int idx = sidx[rr];
        wsq[(size_t)(r0 + rr) * 32 + c4] = wv[(size_t)idx * 32 + c4];
    }

    // Column sums of q over this block's 64 rows (L2-hot rows of W)
    const int d = tid & 127, g = tid >> 7;
    float s = 0.0f;
    for (int rr = g; rr < 64; rr += 2) s += W[(size_t)sidx[rr] * 128 + d];
    sh[g][d] = s;
    __syncthreads();
    if (g == 0) atomicAdd(ws + WS_SQ + d, sh[0][d] + sh[1][d]);
}

// quantized[i][j][:] = q[i]. 537 MB stream write; 8192 blocks x 64 KB.
// Block 0 additionally computes the loss scalar first (from precomputed
// sq/Sq2/x2/sx). Byte-identical to the proven 622.7 us version.
__global__ __launch_bounds__(256) void k_bcast(float* __restrict__ out,
                                               const float* __restrict__ ws) {
    const int bid = blockIdx.x, tid = threadIdx.x;
    if (bid == 0) {
        __shared__ float sh[256];
        float dotv = (tid < 128) ? ws[WS_SX + tid] * ws[WS_SQ + tid] : 0.0f;
        float sx2 = 0.0f;
        for (int r = tid; r < 1024; r += 256) sx2 += ws[WS_X2 + r];
        sh[tid] = dotv;
        __syncthreads();
        for (int s = 128; s > 0; s >>= 1) {
            if (tid < s) sh[tid] += sh[tid + s];
            __syncthreads();
        }
        const float dot = sh[0];
        __syncthreads();
        sh[tid] = sx2;
        __syncthreads();
        for (int s = 128; s > 0; s >>= 1) {
            if (tid < s) sh[tid] += sh[tid + s];
            __syncthreads();
        }
        if (tid == 0) {
            double Sx2 = (double)sh[0], Sq2 = (double)ws[WS_SQ2];
            double loss = 1.25 * (1024.0 * Sx2 + 1024.0 * Sq2 - 2.0 * (double)dot) / 134217728.0;
            out[LOSS_OFF] = (float)loss;
        }
        __syncthreads();
    }
    const int i = bid >> 3;          // row 0..1023
    const int e = bid & 7;           // eighth of the j range
    const int t = tid & 31;
    const vfloat4* src = (const vfloat4*)(ws + WS_Q) + (size_t)i * 32;
    vfloat4 qv = src[t];
    vfloat4* dst = (vfloat4*)out + (size_t)i * 32768 + t;
    const int jend = e * 128 + 128;
    for (int j = e * 128 + (tid >> 5); j < jend; j += 8) {
        dst[(size_t)j * 32] = qv;
    }
}

extern "C" void kernel_launch(void* const* d_in, const int* in_sizes, int n_in,
                              void* d_out, int out_size, void* d_ws, size_t ws_size,
                              hipStream_t stream) {
    const float* x = (const float*)d_in[0]; // 1024 x 128
    const float* W = (const float*)d_in[1]; // 8192 x 128
    float* out = (float*)d_out;
    float* ws = (float*)d_ws;

    hipLaunchKernelGGL(k_prep, dim3(40), dim3(256), 0, stream, x, W, ws);
    hipLaunchKernelGGL(k_score, dim3(64, 16), dim3(256), 0, stream, x, W,
                       ws + WS_W2, ws + WS_X2, ws + WS_PVAL, (int*)(ws + WS_PIDX));
    hipLaunchKernelGGL(k_argmin, dim3(16), dim3(256), 0, stream, W, ws + WS_W2,
                       ws + WS_PVAL, (const int*)(ws + WS_PIDX), out, ws);
    hipLaunchKernelGGL(k_bcast, dim3(8192), dim3(256), 0, stream, out, ws);
}

// Round 9
// 617.646 us; speedup vs baseline: 1.3355x; 1.0049x over previous
//
#include <hip/hip_runtime.h>
#include <stdint.h>

typedef float vfloat4 __attribute__((ext_vector_type(4)));

// B=1024, N=8192, D=128
// out layout (floats): quantized[1024][1024][128] | ind[1024] | loss[1]
static const long long QN       = 134217728LL;
static const long long IND_OFF  = QN;
static const long long LOSS_OFF = QN + 1024;

// ws layout (float offsets). ws is 2 GiB; we use ~1.1 MB.
#define WS_W2    0        // 8192 floats
#define WS_X2    8192     // 1024
#define WS_SX    9216     // 128
#define WS_SQ    9344     // 128
#define WS_SQ2   9472     // 1
#define WS_PVAL  16384    // 65536 floats (1024 x 64)
#define WS_PIDX  81920    // 65536 ints
#define WS_Q     147456   // 131072 floats (1024 x 128 gathered codes)

// Fused prep: blocks 0-31 w2 rows; 32-35 x2 rows; 36-39 x column-sums
// (each block owns 32 columns — no atomics) + block 36 zeros sq/Sq2.
// Byte-identical to the proven 620.7 us version.
__global__ __launch_bounds__(256) void k_prep(const float* __restrict__ x,
                                              const float* __restrict__ W,
                                              float* __restrict__ ws) {
    const int b = blockIdx.x, tid = threadIdx.x;
    if (b < 36) {
        const float4* pr = (b < 32) ? ((const float4*)W + (size_t)(b * 256 + tid) * 32)
                                    : ((const float4*)x + (size_t)((b - 32) * 256 + tid) * 32);
        float s = 0.0f;
#pragma unroll 8
        for (int t = 0; t < 32; ++t) {
            float4 v = pr[t];
            s += v.x * v.x + v.y * v.y + v.z * v.z + v.w * v.w;
        }
        if (b < 32) ws[WS_W2 + b * 256 + tid] = s;
        else        ws[WS_X2 + (b - 32) * 256 + tid] = s;
    } else {
        __shared__ float sh[8][32];
        const int c = tid & 31, g = tid >> 5;
        const int col = (b - 36) * 32 + c;
        float sum = 0.0f;
        for (int r = g; r < 1024; r += 8) sum += x[(size_t)r * 128 + col];
        sh[g][c] = sum;
        __syncthreads();
        if (g == 0) {
            float t = 0.0f;
#pragma unroll
            for (int gg = 0; gg < 8; ++gg) t += sh[gg][c];
            ws[WS_SX + col] = t;
        }
        if (b == 36 && tid < 129) ws[WS_SQ + tid] = 0.0f; // sq[128] + Sq2
    }
}

// dist[m][n] with the reference's fp32 rounding:
//   t = x2[m] - 2*dot(x_m,W_n); s = t + w2[n]
// ROUND-9 CHANGE (B-fragment read pattern only): per-thread j-tile goes from
// 8 contiguous cols (Wst[k][tx*8], 16 addrs @ 32B stride -> 4-way bank
// conflict, 1.58x) to two groups of 4 (tx*4 and 64+tx*4: 16 addrs @ 16B
// stride -> 2-way = conflict-free). Each (m,n) keeps the identical k-order
// FMA chain -> bit-identical acc values; per-thread scan order remains
// index-ascending -> pval/pidx bit-identical. Everything else byte-identical
// to the proven 620.7 us version.
__global__ __launch_bounds__(256, 4) void k_score(
    const float* __restrict__ x, const float* __restrict__ W,
    const float* __restrict__ w2, const float* __restrict__ x2,
    float* __restrict__ pval, int* __restrict__ pidx) {
    __shared__ float Xs[32][68];   // [k][m], +4 pad
    __shared__ float Wst[32][132]; // [k][n], +4 pad
    const int tid = threadIdx.x;
    const int tx = tid & 15, ty = tid >> 4;
    const int n0 = blockIdx.x * 128, m0 = blockIdx.y * 64;
    const float4* xv = (const float4*)x;
    const float4* wv = (const float4*)W;

    float acc[4][8];
#pragma unroll
    for (int i = 0; i < 4; ++i)
#pragma unroll
        for (int j = 0; j < 8; ++j) acc[i][j] = 0.0f;

    for (int kc = 0; kc < 4; ++kc) {
#pragma unroll
        for (int it = 0; it < 2; ++it) {   // x tile: 64 rows x 8 float4
            int f = it * 256 + tid;
            int m = f >> 3, kq = f & 7;
            float4 a = xv[(size_t)(m0 + m) * 32 + kc * 8 + kq];
            Xs[kq * 4 + 0][m] = a.x;
            Xs[kq * 4 + 1][m] = a.y;
            Xs[kq * 4 + 2][m] = a.z;
            Xs[kq * 4 + 3][m] = a.w;
        }
#pragma unroll
        for (int it = 0; it < 4; ++it) {   // W tile: 128 rows x 8 float4
            int f = it * 256 + tid;
            int n = f >> 3, kq = f & 7;
            float4 b = wv[(size_t)(n0 + n) * 32 + kc * 8 + kq];
            Wst[kq * 4 + 0][n] = b.x;
            Wst[kq * 4 + 1][n] = b.y;
            Wst[kq * 4 + 2][n] = b.z;
            Wst[kq * 4 + 3][n] = b.w;
        }
        __syncthreads();
#pragma unroll 8
        for (int k = 0; k < 32; ++k) {
            float4 a0 = *(const float4*)&Xs[k][ty * 4];
            float4 b0 = *(const float4*)&Wst[k][tx * 4];
            float4 b1 = *(const float4*)&Wst[k][64 + tx * 4];
            float af[4] = {a0.x, a0.y, a0.z, a0.w};
            float bf[8] = {b0.x, b0.y, b0.z, b0.w, b1.x, b1.y, b1.z, b1.w};
#pragma unroll
            for (int i = 0; i < 4; ++i)
#pragma unroll
                for (int j = 0; j < 8; ++j) acc[i][j] += af[i] * bf[j];
        }
        __syncthreads();
    }

    // j<4 -> col n0+tx*4+j ; j>=4 -> col n0+64+tx*4+(j-4)
    float w2v[8];
#pragma unroll
    for (int j = 0; j < 4; ++j) w2v[j] = w2[n0 + tx * 4 + j];
#pragma unroll
    for (int j = 4; j < 8; ++j) w2v[j] = w2[n0 + 64 + tx * 4 + (j - 4)];

#pragma unroll
    for (int i = 0; i < 4; ++i) {
        const int row = m0 + ty * 4 + i;
        const float xxv = x2[row];
        float bestv;
        int besti = n0 + tx * 4;
        {
            float t = xxv - 2.0f * acc[i][0];
            bestv = t + w2v[0];
        }
#pragma unroll
        for (int j = 1; j < 8; ++j) {
            float t = xxv - 2.0f * acc[i][j];
            float s = t + w2v[j];
            const int col = (j < 4) ? (n0 + tx * 4 + j) : (n0 + 64 + tx * 4 + (j - 4));
            if (s < bestv) { bestv = s; besti = col; }
        }
        for (int off = 1; off < 16; off <<= 1) {
            float ov = __shfl_xor(bestv, off, 64);
            int oi = __shfl_xor(besti, off, 64);
            if (ov < bestv || (ov == bestv && oi < besti)) { bestv = ov; besti = oi; }
        }
        if (tx == 0) {
            pval[row * 64 + blockIdx.x] = bestv;
            pidx[row * 64 + blockIdx.x] = besti;
        }
    }
}

// Final argmin per row. 16 blocks x 64 rows. Wave-per-row butterfly min with
// (val, min-idx) tie-break == first-occurrence scan, since pidx from
// column-chunk c only contains indices in [c*128, c*128+128).
// Byte-identical to the proven 620.7 us version.
__global__ __launch_bounds__(256) void k_argmin(
    const float* __restrict__ W, const float* __restrict__ w2,
    const float* __restrict__ pval, const int* __restrict__ pidx,
    float* __restrict__ out, float* __restrict__ ws) {
    __shared__ int sidx[64];
    __shared__ float sh[2][128];
    const int tid = threadIdx.x;
    const int w = tid >> 6, lane = tid & 63;
    const int r0 = blockIdx.x * 64;
    float q2 = 0.0f;
#pragma unroll 4
    for (int it = 0; it < 16; ++it) {
        const int rr = it * 4 + w;       // local row 0..63
        const int r = r0 + rr;
        float bestv = pval[r * 64 + lane];
        int besti = pidx[r * 64 + lane];
        for (int off = 1; off < 64; off <<= 1) {
            float ov = __shfl_xor(bestv, off, 64);
            int oi = __shfl_xor(besti, off, 64);
            if (ov < bestv || (ov == bestv && oi < besti)) { bestv = ov; besti = oi; }
        }
        if (lane == 0) {
            out[IND_OFF + r] = (float)besti;
            sidx[rr] = besti;
            q2 += w2[besti];             // ||q_r||^2 == w2[ind_r]
        }
    }
    if (lane == 0) atomicAdd(ws + WS_SQ2, q2);
    __syncthreads();

    // Coalesced q gather into ws: 8 iters of (8 rows x 32 float4)
    const int c4 = tid & 31, rg = tid >> 5;
    float4* wsq = (float4*)(ws + WS_Q);
    const float4* wv = (const float4*)W;
#pragma unroll
    for (int it = 0; it < 8; ++it) {
        int rr = it * 8 + rg;
        int idx = sidx[rr];
        wsq[(size_t)(r0 + rr) * 32 + c4] = wv[(size_t)idx * 32 + c4];
    }

    // Column sums of q over this block's 64 rows (L2-hot rows of W)
    const int d = tid & 127, g = tid >> 7;
    float s = 0.0f;
    for (int rr = g; rr < 64; rr += 2) s += W[(size_t)sidx[rr] * 128 + d];
    sh[g][d] = s;
    __syncthreads();
    if (g == 0) atomicAdd(ws + WS_SQ + d, sh[0][d] + sh[1][d]);
}

// quantized[i][j][:] = q[i]. 537 MB stream write; 8192 blocks x 64 KB.
// Block 0 additionally computes the loss scalar first (from precomputed
// sq/Sq2/x2/sx). Byte-identical to the proven 620.7 us version.
__global__ __launch_bounds__(256) void k_bcast(float* __restrict__ out,
                                               const float* __restrict__ ws) {
    const int bid = blockIdx.x, tid = threadIdx.x;
    if (bid == 0) {
        __shared__ float sh[256];
        float dotv = (tid < 128) ? ws[WS_SX + tid] * ws[WS_SQ + tid] : 0.0f;
        float sx2 = 0.0f;
        for (int r = tid; r < 1024; r += 256) sx2 += ws[WS_X2 + r];
        sh[tid] = dotv;
        __syncthreads();
        for (int s = 128; s > 0; s >>= 1) {
            if (tid < s) sh[tid] += sh[tid + s];
            __syncthreads();
        }
        const float dot = sh[0];
        __syncthreads();
        sh[tid] = sx2;
        __syncthreads();
        for (int s = 128; s > 0; s >>= 1) {
            if (tid < s) sh[tid] += sh[tid + s];
            __syncthreads();
        }
        if (tid == 0) {
            double Sx2 = (double)sh[0], Sq2 = (double)ws[WS_SQ2];
            double loss = 1.25 * (1024.0 * Sx2 + 1024.0 * Sq2 - 2.0 * (double)dot) / 134217728.0;
            out[LOSS_OFF] = (float)loss;
        }
        __syncthreads();
    }
    const int i = bid >> 3;          // row 0..1023
    const int e = bid & 7;           // eighth of the j range
    const int t = tid & 31;
    const vfloat4* src = (const vfloat4*)(ws + WS_Q) + (size_t)i * 32;
    vfloat4 qv = src[t];
    vfloat4* dst = (vfloat4*)out + (size_t)i * 32768 + t;
    const int jend = e * 128 + 128;
    for (int j = e * 128 + (tid >> 5); j < jend; j += 8) {
        dst[(size_t)j * 32] = qv;
    }
}

extern "C" void kernel_launch(void* const* d_in, const int* in_sizes, int n_in,
                              void* d_out, int out_size, void* d_ws, size_t ws_size,
                              hipStream_t stream) {
    const float* x = (const float*)d_in[0]; // 1024 x 128
    const float* W = (const float*)d_in[1]; // 8192 x 128
    float* out = (float*)d_out;
    float* ws = (float*)d_ws;

    hipLaunchKernelGGL(k_prep, dim3(40), dim3(256), 0, stream, x, W, ws);
    hipLaunchKernelGGL(k_score, dim3(64, 16), dim3(256), 0, stream, x, W,
                       ws + WS_W2, ws + WS_X2, ws + WS_PVAL, (int*)(ws + WS_PIDX));
    hipLaunchKernelGGL(k_argmin, dim3(16), dim3(256), 0, stream, W, ws + WS_W2,
                       ws + WS_PVAL, (const int*)(ws + WS_PIDX), out, ws);
    hipLaunchKernelGGL(k_bcast, dim3(8192), dim3(256), 0, stream, out, ws);
}